// Round 6
// baseline (24.974 us; speedup 1.0000x reference)
//
#include <hip/hip_runtime.h>

// out[k][j] = max( x1[k][j], max_i( W[i][j]*x0[k][i] + B[i][j] + C_norm[i][j] ) )
// N=4096, D=256, f32 in/out. f16 packed math (validated absmax 0.031 < 0.101).
//
// prep: x0 -> x0T[i][k] f16 (LDS-tiled transpose); W -> f16; A=B+C -> f16.
// main: 256 blocks x 512 thr (64k x 64j tile, full i=256). W/A live in
// REGISTERS (16 i-rows x 8 j per thread, 2 generations; gen1 loads pipelined
// into gen0's dead regs). x0T tile (256i x 64k, 32KB) staged to LDS once.
// Inner loop: 1 conflict-free ds_read_b128 -> 64 pk-f16 insts. One stage
// barrier. LDS tree-merge across the 8 i-slice waves; distributed epilogue.

typedef _Float16 h16;
typedef h16 h2  __attribute__((ext_vector_type(2)));
typedef h16 h8v __attribute__((ext_vector_type(8)));
typedef float f32x4 __attribute__((ext_vector_type(4)));

constexpr int Dk = 256;
constexpr int NK = 4096;

// ---------------- prep ----------------
__global__ __launch_bounds__(256)
void prep(const float* __restrict__ x0, const float* __restrict__ Cn,
          const float* __restrict__ W, const float* __restrict__ Bm,
          h16* __restrict__ x0T, h16* __restrict__ Wh, h16* __restrict__ Ah) {
  const int b = blockIdx.x;
  const int t = threadIdx.x;
  if (b < 256) {
    // transpose+convert one 64k x 64i tile of x0 into x0T[i][k]
    __shared__ float tl[64][65];
    const int kt = b >> 2;            // 64 k-tiles
    const int it = b & 3;             // 4 i-tiles
#pragma unroll
    for (int q = 0; q < 4; ++q) {
      const int idx = q * 256 + t;
      const int row = idx >> 4;             // k row 0..63
      const int c4  = (idx & 15) * 4;       // i col
      *reinterpret_cast<f32x4*>(&tl[row][c4]) =
          *reinterpret_cast<const f32x4*>(&x0[(kt * 64 + row) * Dk + it * 64 + c4]);
    }
    __syncthreads();
#pragma unroll
    for (int q = 0; q < 2; ++q) {
      const int c = q * 256 + t;            // 512 chunks
      const int i  = c >> 3;                // 0..63
      const int k8 = (c & 7) * 8;
      h8v h;
#pragma unroll
      for (int u = 0; u < 8; ++u) h[u] = (h16)tl[k8 + u][i];
      *reinterpret_cast<h8v*>(&x0T[(size_t)(it * 64 + i) * NK + kt * 64 + k8]) = h;
    }
  } else {
    // W and A = B + C_norm -> f16 (32 blocks x 256 thr x 8 elems = 65536)
    const int idx = ((b - 256) * 256 + t) * 8;
    const f32x4 w0 = *reinterpret_cast<const f32x4*>(&W[idx]);
    const f32x4 w1 = *reinterpret_cast<const f32x4*>(&W[idx + 4]);
    const f32x4 b0 = *reinterpret_cast<const f32x4*>(&Bm[idx]);
    const f32x4 b1 = *reinterpret_cast<const f32x4*>(&Bm[idx + 4]);
    const f32x4 c0 = *reinterpret_cast<const f32x4*>(&Cn[idx]);
    const f32x4 c1 = *reinterpret_cast<const f32x4*>(&Cn[idx + 4]);
    const f32x4 a0 = b0 + c0, a1 = b1 + c1;
    h8v hw, ha;
#pragma unroll
    for (int u = 0; u < 4; ++u) {
      hw[u] = (h16)w0[u]; hw[u + 4] = (h16)w1[u];
      ha[u] = (h16)a0[u]; ha[u + 4] = (h16)a1[u];
    }
    *reinterpret_cast<h8v*>(&Wh[idx]) = hw;
    *reinterpret_cast<h8v*>(&Ah[idx]) = ha;
  }
}

// ---------------- main ----------------
__global__ __launch_bounds__(512, 2)
void mp_main(const h16* __restrict__ x0T, const h16* __restrict__ Wh,
             const h16* __restrict__ Ah, const float* __restrict__ x1,
             float* __restrict__ out) {
  __shared__ h16 Xl[256 * 64];   // [i][k] 32KB; reused as merge scratch

  const int tid = threadIdx.x;
  const int w   = tid >> 6;          // wave 0..7: i-slice owner
  const int l   = tid & 63;
  const int tk  = l >> 3;            // k-group: k_local = tk*8 + kk
  const int tj  = l & 7;             // j-group: j = j0 + tj*8 + ...
  const int k0  = (blockIdx.x >> 2) * 64;
  const int j0  = (blockIdx.x & 3) * 64;

  // ---- gen0 W/A register loads (issued first; L2-hot, wave-coalesced) ----
  h8v wr[16], ar[16];
#pragma unroll
  for (int r = 0; r < 16; ++r) {
    const int i = w * 16 + r;
    wr[r] = *reinterpret_cast<const h8v*>(&Wh[i * Dk + j0 + tj * 8]);
    ar[r] = *reinterpret_cast<const h8v*>(&Ah[i * Dk + j0 + tj * 8]);
  }

  // ---- stage x0T tile once (linear, coalesced) ----
#pragma unroll
  for (int p = 0; p < 4; ++p) {
    const int c  = p * 512 + tid;          // 2048 x 16B chunks
    const int ir = c >> 3;                 // i 0..255
    const int k8 = (c & 7) * 8;
    const h8v v = *reinterpret_cast<const h8v*>(&x0T[(size_t)ir * NK + k0 + k8]);
    *reinterpret_cast<h8v*>(&Xl[ir * 64 + k8]) = v;
  }
  __syncthreads();

  h2 acc[8][4];
#pragma unroll
  for (int kk = 0; kk < 8; ++kk)
#pragma unroll
    for (int p = 0; p < 4; ++p)
      acc[kk][p] = h2{(h16)(-60000.0f), (h16)(-60000.0f)};

#define KSTEP(K) {                                                              \
    const h2 xb = __builtin_shufflevector(xrv, xrv, (K), (K));                  \
    acc[K][0] = __builtin_elementwise_max(acc[K][0], __builtin_elementwise_fma(wp0, xb, ap0)); \
    acc[K][1] = __builtin_elementwise_max(acc[K][1], __builtin_elementwise_fma(wp1, xb, ap1)); \
    acc[K][2] = __builtin_elementwise_max(acc[K][2], __builtin_elementwise_fma(wp2, xb, ap2)); \
    acc[K][3] = __builtin_elementwise_max(acc[K][3], __builtin_elementwise_fma(wp3, xb, ap3)); \
  }

#define RSTEP(WV, AV) {                                                         \
    const h2 wp0 = __builtin_shufflevector(WV, WV, 0, 1);                       \
    const h2 wp1 = __builtin_shufflevector(WV, WV, 2, 3);                       \
    const h2 wp2 = __builtin_shufflevector(WV, WV, 4, 5);                       \
    const h2 wp3 = __builtin_shufflevector(WV, WV, 6, 7);                       \
    const h2 ap0 = __builtin_shufflevector(AV, AV, 0, 1);                       \
    const h2 ap1 = __builtin_shufflevector(AV, AV, 2, 3);                       \
    const h2 ap2 = __builtin_shufflevector(AV, AV, 4, 5);                       \
    const h2 ap3 = __builtin_shufflevector(AV, AV, 6, 7);                       \
    KSTEP(0) KSTEP(1) KSTEP(2) KSTEP(3) KSTEP(4) KSTEP(5) KSTEP(6) KSTEP(7)    \
  }

  // ---- gen 0: i in [w*16, w*16+16); pipeline gen1 W/A into dead regs ----
#pragma unroll
  for (int r = 0; r < 16; ++r) {
    const h8v xrv = *reinterpret_cast<const h8v*>(&Xl[(w * 16 + r) * 64 + tk * 8]);
    RSTEP(wr[r], ar[r])
    const int i1 = 128 + w * 16 + r;
    wr[r] = *reinterpret_cast<const h8v*>(&Wh[i1 * Dk + j0 + tj * 8]);
    ar[r] = *reinterpret_cast<const h8v*>(&Ah[i1 * Dk + j0 + tj * 8]);
  }
  // ---- gen 1: i in [128 + w*16, +16) ----
#pragma unroll
  for (int r = 0; r < 16; ++r) {
    const h8v xrv = *reinterpret_cast<const h8v*>(&Xl[(128 + w * 16 + r) * 64 + tk * 8]);
    RSTEP(wr[r], ar[r])
  }
#undef RSTEP
#undef KSTEP

  __syncthreads();   // all Xl reads done; reuse as merge scratch

  // ---- tree merge across the 8 waves ----
  uint4* mrg = reinterpret_cast<uint4*>(Xl);
  auto wslot = [&](int s) {
#pragma unroll
    for (int kk = 0; kk < 8; ++kk) {
      uint4 u;
      u.x = __builtin_bit_cast(unsigned int, acc[kk][0]);
      u.y = __builtin_bit_cast(unsigned int, acc[kk][1]);
      u.z = __builtin_bit_cast(unsigned int, acc[kk][2]);
      u.w = __builtin_bit_cast(unsigned int, acc[kk][3]);
      mrg[(s * 8 + kk) * 64 + l] = u;
    }
  };
  auto rmerge = [&](int s) {
#pragma unroll
    for (int kk = 0; kk < 8; ++kk) {
      const uint4 u = mrg[(s * 8 + kk) * 64 + l];
      acc[kk][0] = __builtin_elementwise_max(acc[kk][0], __builtin_bit_cast(h2, u.x));
      acc[kk][1] = __builtin_elementwise_max(acc[kk][1], __builtin_bit_cast(h2, u.y));
      acc[kk][2] = __builtin_elementwise_max(acc[kk][2], __builtin_bit_cast(h2, u.z));
      acc[kk][3] = __builtin_elementwise_max(acc[kk][3], __builtin_bit_cast(h2, u.w));
    }
  };

  if (w >= 4) wslot(w - 4);
  __syncthreads();
  if (w < 4) rmerge(w);
  __syncthreads();
  if (w == 2 || w == 3) wslot(w - 2);
  __syncthreads();
  if (w < 2) rmerge(w);
  __syncthreads();
  if (w == 1) wslot(0);
  __syncthreads();
  if (w == 0) { rmerge(0); wslot(0); }
  __syncthreads();

  // ---- distributed epilogue: fold x1, f32 store ----
  {
    const uint4 u = mrg[w * 64 + l];   // contiguous = mrg[tid]
    const h2 p0 = __builtin_bit_cast(h2, u.x);
    const h2 p1 = __builtin_bit_cast(h2, u.y);
    const h2 p2 = __builtin_bit_cast(h2, u.z);
    const h2 p3 = __builtin_bit_cast(h2, u.w);
    const int k = k0 + (l >> 3) * 8 + w;
    const int j = j0 + (l & 7) * 8;
    f32x4 o0 = { (float)p0[0], (float)p0[1], (float)p1[0], (float)p1[1] };
    f32x4 o1 = { (float)p2[0], (float)p2[1], (float)p3[0], (float)p3[1] };
    const f32x4* xg = reinterpret_cast<const f32x4*>(&x1[k * Dk + j]);
    o0 = __builtin_elementwise_max(o0, xg[0]);
    o1 = __builtin_elementwise_max(o1, xg[1]);
    f32x4* og = reinterpret_cast<f32x4*>(&out[k * Dk + j]);
    og[0] = o0;
    og[1] = o1;
  }
}

extern "C" void kernel_launch(void* const* d_in, const int* in_sizes, int n_in,
                              void* d_out, int out_size, void* d_ws, size_t ws_size,
                              hipStream_t stream) {
  const float* x0 = (const float*)d_in[0];
  const float* x1 = (const float*)d_in[1];
  const float* Cn = (const float*)d_in[2];
  const float* W  = (const float*)d_in[3];
  const float* Bm = (const float*)d_in[4];
  float* out = (float*)d_out;

  h16* x0T = (h16*)d_ws;                                          // 2 MB
  h16* Wh  = (h16*)((char*)d_ws + (size_t)NK * Dk * 2);           // 128 KB
  h16* Ah  = (h16*)((char*)d_ws + (size_t)NK * Dk * 2 + Dk * Dk * 2);

  hipLaunchKernelGGL(prep, dim3(256 + 32), dim3(256), 0, stream,
                     x0, Cn, W, Bm, x0T, Wh, Ah);
  hipLaunchKernelGGL(mp_main, dim3((NK / 64) * 4), dim3(512), 0, stream,
                     x0T, Wh, Ah, x1, out);
}